// Round 8
// baseline (363.225 us; speedup 1.0000x reference)
//
#include <hip/hip_runtime.h>
#include <hip/hip_bf16.h>

typedef unsigned short ushort_t;
typedef __attribute__((ext_vector_type(8))) short short8;
typedef __attribute__((ext_vector_type(4))) float f32x4;

#define NCOMP    8
#define CIN      512
#define COUT     256
#define H        64
#define HP       66      // padded spatial dim (halo 1 each side)
#define OHW      128
#define NB       8

// Cayley-Dickson |comp| table for n=8; sign(i,j)=+1 iff i>=j.
__device__ const int d_idx8[8][8] = {
    {0,1,2,1,4,3,2,3},
    {1,0,3,2,5,4,1,2},
    {2,1,0,1,6,5,4,3},
    {3,2,1,0,7,6,5,4},
    {4,3,2,3,0,1,2,1},
    {5,4,1,2,1,0,3,2},
    {6,5,4,3,2,1,0,1},
    {7,6,5,4,3,2,1,0}};

// Tap tables: output parity p, tap index a: kernel index kh, input offset dh.
__device__ const int kh_tab[2][2] = {{1,3},{0,2}};
__device__ const int dh_tab[2][2] = {{0,-1},{1,0}};

// ---------------- prep: x -> padded, transposed, bf16 (fused halo) ----------
// Split over ic-halves (blockIdx.z) for 2x blocks / latency hiding.
__global__ void prep_x2(const float* __restrict__ x, ushort_t* __restrict__ xpadT) {
    __shared__ __align__(16) ushort_t lds[64 * 256];
    const int t  = threadIdx.x;       // 0..255
    const int b  = blockIdx.y;
    const int zh = blockIdx.z;        // ic half (0/1); pad path: which pad row
    const int ihb = blockIdx.x;       // 0..64; 64 => pad row (zh selects 0/65)

    if (ihb == 64) {                  // ih_pad = 0 (zh=0) or 65 (zh=1)
        short8 z8 = {0,0,0,0,0,0,0,0};
        ushort_t* r0 = xpadT + ((size_t)b * HP + (zh ? 65 : 0)) * HP * CIN;
        for (int e = t; e < (HP * CIN) / 8; e += 256)
            *(short8*)(r0 + e * 8) = z8;
        return;
    }
    const int ih = ihb;

    // ---- phase 1: load + convert + transposed swizzled LDS store ----
    const int iv      = t & 15;       // float4 index within row (iw = 4*iv+j)
    const int ic_base = t >> 4;       // 0..15
    const float* xr = x + ((size_t)(b * CIN + zh * 256)) * H * H + (size_t)ih * H;
#pragma unroll 8
    for (int r = 0; r < 16; ++r) {
        const int icl = r * 16 + ic_base;            // 0..255 within half
        const float4 v = *(const float4*)(xr + (size_t)icl * H * H + iv * 4);
        const int swz = icl ^ (iv << 3);             // bijective within [0,256)
        __hip_bfloat16 h0 = __float2bfloat16(v.x);
        __hip_bfloat16 h1 = __float2bfloat16(v.y);
        __hip_bfloat16 h2 = __float2bfloat16(v.z);
        __hip_bfloat16 h3 = __float2bfloat16(v.w);
        lds[(iv * 4 + 0) * 256 + swz] = *(ushort_t*)&h0;
        lds[(iv * 4 + 1) * 256 + swz] = *(ushort_t*)&h1;
        lds[(iv * 4 + 2) * 256 + swz] = *(ushort_t*)&h2;
        lds[(iv * 4 + 3) * 256 + swz] = *(ushort_t*)&h3;
    }
    __syncthreads();

    // ---- phase 2: contiguous interior write (this ic half) + halo cells ----
    ushort_t* rowc = xpadT + (((size_t)b * HP + ih + 1) * HP) * CIN; // iw_pad=0
    ushort_t* dstb = rowc + CIN + zh * 256;                          // iw_pad=1
#pragma unroll
    for (int r = 0; r < 8; ++r) {
        const int e    = r * 256 + t;                // 0..2047
        const int iw   = e >> 5;                     // 0..63
        const int icl0 = (e & 31) * 8;               // 0..255 step 8
        const int off  = iw * 256 + (icl0 ^ ((iw >> 2) << 3));
        *(short8*)(dstb + (size_t)iw * CIN + icl0) = *(const short8*)(lds + off);
    }
    if (zh == 0 && t < 128) {                        // halo cells iw_pad 0 and 65
        short8 z8 = {0,0,0,0,0,0,0,0};
        const int l = t & 63;
        ushort_t* hc = (t < 64) ? rowc : (rowc + 65 * CIN);
        *(short8*)(hc + l * 8) = z8;
    }
}

// ---------------- prep: fused bf16 weights + bias ----------------
__global__ void prep_w(const float* __restrict__ W, const float* __restrict__ bias,
                       ushort_t* __restrict__ Abf, float* __restrict__ bbig) {
    const int t = blockIdx.x * blockDim.x + threadIdx.x;
    if (t < 4 * 64 * 256 * 32) {
        int kin = t & 31;
        int oc  = (t >> 5) & 255;
        int ks  = (t >> 13) & 63;
        int cls = t >> 19;
        int k  = ks * 32 + kin;
        int a  = k >> 10, c = (k >> 9) & 1, ic = k & 511;
        int ph = cls >> 1, pw = cls & 1;
        int kh = kh_tab[ph][a], kw = kh_tab[pw][c];
        int i = oc >> 5, co = oc & 31;
        int j = ic >> 6, ci = ic & 63;
        float s = (i >= j) ? 1.0f : -1.0f;
        float v = s * W[(((size_t)(d_idx8[i][j] * 64 + ci) * 32 + co) * 4 + kh) * 4 + kw];
        __hip_bfloat16 h = __float2bfloat16(v);
        Abf[t] = *(ushort_t*)&h;
    }
    if (t < COUT) {
        int i = t >> 5, co = t & 31;
        float acc = 0.0f;
        for (int j = 0; j < NCOMP; ++j)
            acc += ((i >= j) ? 1.0f : -1.0f) * bias[d_idx8[i][j] * 32 + co];
        bbig[t] = acc;
    }
}

// ---------------- main: 128x256-tile implicit-GEMM ----------------
// B (pixels) LDS-staged, 3 x 16KB buffers; A (weights) DIRECT global->reg
// (L1/L2-resident stream, shared across ntile blocks) -> LDS traffic/step
// cut 88KB -> 48KB per block.  Counted-vmcnt semantics emerge from the
// compiler's exact per-dependency waits:
//   at MFMA(n) it must retire A(n) [issued end of step n-1]; the in-order
//   vmcnt thereby retires Bstage(n+1) (issued earlier) and KEEPS Bstage(n+2)
//   (issued this step) in flight -> never drains to 0 mid-loop (T4).
__device__ __forceinline__ void async16(void* lds_dst, const void* g_src) {
    __builtin_amdgcn_global_load_lds(
        (const __attribute__((address_space(1))) unsigned int*)g_src,
        (__attribute__((address_space(3))) unsigned int*)lds_dst,
        16, 0, 0);
}

#define BB0 0
#define BB1 16384
#define BB2 32768

// Stage step NS's B tile (16KB) into buffer at byte base CB (2 async16/thread).
#define STAGE_B(NS, CB)                                                        \
  {                                                                            \
    const int ns_  = (NS);                                                     \
    const int na_  = ns_ >> 5;                                                 \
    const int ncb_ = (ns_ >> 4) & 1;                                           \
    const int go_  = ((na_ ? dh1 : dh0) * HP + (ncb_ ? dw1 : dw0)) * CIN       \
                     + (ns_ & 15) * 32;                                        \
    async16(sb + (CB) + t * 16,        base_lo + go_);                         \
    async16(sb + (CB) + 8192 + t * 16, base_hi + go_);                         \
  }

// A-frags for step NS direct from global (plain quad chunk — the LDS
// srcc/soff swizzle pair cancels, verified algebraically).
#define LOADA(NS)                                                              \
    _Pragma("unroll")                                                          \
    for (int s = 0; s < 4; ++s)                                                \
      af[s] = *(const short8*)(Aptr + (size_t)(NS) * 8192 + s * 512);

// One K-step: barrier publishes buf(NS_READ); stage NS_ST; ds_read B-frags;
// MFMA on af (loaded last step) + bf; then load af for next step (WAR after
// last MFMA use — in-place, no extra registers).
#define STEP(NS_ST, CB_ST, CB_RD, NS_A)                                        \
  {                                                                            \
    __builtin_amdgcn_s_barrier();                                              \
    __builtin_amdgcn_sched_barrier(0);                                         \
    STAGE_B(NS_ST, CB_ST);                                                     \
    short8 bf[4];                                                              \
    _Pragma("unroll")                                                          \
    for (int s = 0; s < 4; ++s)                                                \
      bf[s] = *(const short8*)(sb + (CB_RD) + boff + s * 1024);                \
    _Pragma("unroll")                                                          \
    for (int sm = 0; sm < 4; ++sm)                                             \
      _Pragma("unroll")                                                        \
      for (int sn = 0; sn < 4; ++sn)                                           \
        acc[sm][sn] = __builtin_amdgcn_mfma_f32_16x16x32_bf16(                 \
            af[sm], bf[sn], acc[sm][sn], 0, 0, 0);                             \
    LOADA(NS_A);                                                               \
  }

// Tail step: no stage and/or no next-A.
#define STEP_NOST(CB_RD, NS_A)                                                 \
  {                                                                            \
    __builtin_amdgcn_s_barrier();                                              \
    __builtin_amdgcn_sched_barrier(0);                                         \
    short8 bf[4];                                                              \
    _Pragma("unroll")                                                          \
    for (int s = 0; s < 4; ++s)                                                \
      bf[s] = *(const short8*)(sb + (CB_RD) + boff + s * 1024);                \
    _Pragma("unroll")                                                          \
    for (int sm = 0; sm < 4; ++sm)                                             \
      _Pragma("unroll")                                                        \
      for (int sn = 0; sn < 4; ++sn)                                           \
        acc[sm][sn] = __builtin_amdgcn_mfma_f32_16x16x32_bf16(                 \
            af[sm], bf[sn], acc[sm][sn], 0, 0, 0);                             \
    LOADA(NS_A);                                                               \
  }

__launch_bounds__(512, 4)
__global__ void htconv_mfma(const ushort_t* __restrict__ xpadT,
                            const ushort_t* __restrict__ Abf,
                            const float* __restrict__ bbig,
                            float* __restrict__ out) {
    // Three 16KB B-buffers = 48KB LDS -> 2 blocks/CU with headroom.
    __shared__ __align__(16) ushort_t smem[24576];
    char* sb = (char*)smem;

    const int t     = threadIdx.x;            // 0..511
    const int ntile = blockIdx.x;             // 0..15 -> ohh0 = 4*ntile
    const int mtile = blockIdx.y;             // 0..1 (oc half)
    const int cls   = blockIdx.z & 3;
    const int b     = blockIdx.z >> 2;
    const int ph = cls >> 1, pw = cls & 1;
    const int ohh0 = ntile * 4;

    // ---- B staging addresses (srcc pre-swizzle unchanged) ----
    const int srcc = (((t & 3) ^ ((t >> 3) & 3)) * 8);
    const int dh0 = dh_tab[ph][0], dh1 = dh_tab[ph][1];
    const int dw0 = dh_tab[pw][0], dw1 = dh_tab[pw][1];
    const int oww = (t >> 2) & 63;            // pixel col 0..63
    const int rlo = t >> 8;                   // sub-row 0/1 (first load); +2 second
    const ushort_t* base_lo =
        xpadT + (((size_t)b * HP + ohh0 + rlo + 1) * HP + oww + 1) * CIN + srcc;
    const ushort_t* base_hi = base_lo + (size_t)2 * HP * CIN;

    // ---- fragment offsets ----
    const int lane = t & 63, wave = t >> 6;   // 8 waves: 2 M-warps x 4 N-warps
    const int wm = wave >> 2, wn = wave & 3;  // per-wave: 64 oc x 64 px
    const int col = lane & 15, quad = lane >> 4;
    const int soff = (quad ^ ((col >> 1) & 3)) * 16;
    const int boff = (wn * 64 + col) * 64 + soff;   // B rows within buffer

    // A direct-from-global per-lane pointer (row = oc, plain quad chunk).
    const ushort_t* Aptr =
        Abf + (size_t)cls * (64 * 256 * 32)
            + (size_t)(mtile * 128 + wm * 64 + col) * 32 + quad * 8;

    f32x4 acc[4][4];
#pragma unroll
    for (int i = 0; i < 4; ++i)
#pragma unroll
        for (int j = 0; j < 4; ++j)
            acc[i][j] = (f32x4){0.f, 0.f, 0.f, 0.f};

    short8 af[4];

    // ---- prologue: stage B(0),B(1); issue A(0); retire B(0),B(1) only ----
    STAGE_B(0, BB0);
    STAGE_B(1, BB1);
    LOADA(0);
    asm volatile("s_waitcnt vmcnt(4)" ::: "memory");   // B0,B1 landed; A0 in flight

    // ---- 64 K-steps: step s reads buf s%3, stages s+2 into (s+2)%3,
    //      preloads A(s+1).  3x unrolled for static buffer parity. ----
#pragma unroll 1
    for (int i = 0; i < 20; ++i) {
        const int n = 3 * i;
        STEP(n + 2, BB2, BB0, n + 1);   // step n
        STEP(n + 3, BB0, BB1, n + 2);   // step n+1
        STEP(n + 4, BB1, BB2, n + 3);   // step n+2
    }
    // steps 60..63
    STEP(62, BB2, BB0, 61);             // step 60
    STEP(63, BB0, BB1, 62);             // step 61
    STEP_NOST(BB2, 63);                 // step 62
    {                                   // step 63 (no stage, no next A)
        __builtin_amdgcn_s_barrier();
        __builtin_amdgcn_sched_barrier(0);
        short8 bf[4];
#pragma unroll
        for (int s = 0; s < 4; ++s)
            bf[s] = *(const short8*)(sb + BB0 + boff + s * 1024);
#pragma unroll
        for (int sm = 0; sm < 4; ++sm)
#pragma unroll
            for (int sn = 0; sn < 4; ++sn)
                acc[sm][sn] = __builtin_amdgcn_mfma_f32_16x16x32_bf16(
                    af[sm], bf[sn], acc[sm][sn], 0, 0, 0);
    }

    // ---- epilogue: bias + stride-2 scatter store ----
    const int oh = 2 * (ohh0 + wn) + ph;
#pragma unroll
    for (int sm = 0; sm < 4; ++sm) {
#pragma unroll
        for (int r = 0; r < 4; ++r) {
            const int occ = mtile * 128 + wm * 64 + sm * 16 + quad * 4 + r;
            const float bv = bbig[occ];
            float* obase = out + (((size_t)b * COUT + occ) * OHW + oh) * OHW + pw;
#pragma unroll
            for (int sn = 0; sn < 4; ++sn) {
                const int owi = sn * 16 + col;          // pixel col 0..63
                obase[2 * owi] = acc[sm][sn][r] + bv;
            }
        }
    }
}

extern "C" void kernel_launch(void* const* d_in, const int* in_sizes, int n_in,
                              void* d_out, int out_size, void* d_ws, size_t ws_size,
                              hipStream_t stream) {
    const float* x    = (const float*)d_in[0];  // [8,512,64,64]
    const float* W    = (const float*)d_in[1];  // [8,64,32,4,4]
    const float* bias = (const float*)d_in[2];  // [8,32]
    float* out = (float*)d_out;                 // [8,256,128,128]

    ushort_t* xpadT = (ushort_t*)d_ws;                       // 8*66*66*512 elems
    ushort_t* Abf   = xpadT + (size_t)NB * HP * HP * CIN;    // 4*64*256*32 elems
    float*    bbig  = (float*)(Abf + (size_t)4 * 64 * 256 * 32);

    prep_x2<<<dim3(65, NB, 2), 256, 0, stream>>>(x, xpadT);
    prep_w<<<dim3((4 * 64 * 256 * 32) / 256), 256, 0, stream>>>(W, bias, Abf, bbig);
    htconv_mfma<<<dim3(16, 2, 32), 512, 0, stream>>>(xpadT, Abf, bbig, out);
}